// Round 9
// baseline (750.858 us; speedup 1.0000x reference)
//
#include <hip/hip_runtime.h>
#include <math.h>

// Problem constants: B=8, L=512, D=1024, H=16, C=4, Dk=64
#define BB 8
#define LL 512
#define DD 1024
#define HH 16
#define CC 4
#define DK 64
#define NEG_DPI 201.06192982974676f   // 64 * pi

typedef __attribute__((ext_vector_type(8))) short short8;     // MFMA A/B frag (8 bf16)
typedef __attribute__((ext_vector_type(4))) float floatx4;    // MFMA C/D frag
typedef __attribute__((ext_vector_type(8))) unsigned short u16x8;
typedef __attribute__((ext_vector_type(4))) unsigned short u16x4;

// ---------------- helpers ----------------
__device__ inline float block_sum256(float v, float* s_red) {
    int t = threadIdx.x;
    s_red[t] = v; __syncthreads();
    for (int off = 128; off > 0; off >>= 1) {
        if (t < off) s_red[t] += s_red[t + off];
        __syncthreads();
    }
    float r = s_red[0]; __syncthreads();
    return r;
}
__device__ inline float block_max256(float v, float* s_red) {
    int t = threadIdx.x;
    s_red[t] = v; __syncthreads();
    for (int off = 128; off > 0; off >>= 1) {
        if (t < off) s_red[t] = fmaxf(s_red[t], s_red[t + off]);
        __syncthreads();
    }
    float r = s_red[0]; __syncthreads();
    return r;
}
__device__ inline unsigned int fenc(float f) {
    unsigned int b = __float_as_uint(f);
    return (b & 0x80000000u) ? ~b : (b | 0x80000000u);
}
__device__ inline float fdec(unsigned int u) {
    return (u & 0x80000000u) ? __uint_as_float(u ^ 0x80000000u) : __uint_as_float(~u);
}
__device__ inline unsigned short f2bf(float x) {   // RNE fp32 -> bf16 (bit-twiddle)
    unsigned int u = __float_as_uint(x);
    return (unsigned short)((u + 0x7FFFu + ((u >> 16) & 1u)) >> 16);
}
// RNE fp32 -> bf16 via hardware converter; bit-identical to f2bf for finite inputs.
__device__ inline unsigned short f2bf_cvt(float x) {
    __bf16 b = (__bf16)x;
    return __builtin_bit_cast(unsigned short, b);
}
__device__ inline float bf2f(unsigned short h) {
    return __uint_as_float((unsigned int)h << 16);
}
// split 8 fp32 (two float4) into hi/lo bf16 octets — hi converts grouped (pk-packable),
// then residuals, then lo converts grouped.
__device__ inline void split8(const float4 x, const float4 y, u16x8& h, u16x8& l) {
    float c[8] = {x.x, x.y, x.z, x.w, y.x, y.y, y.z, y.w};
    unsigned short hb[8];
#pragma unroll
    for (int j = 0; j < 8; j++) { hb[j] = f2bf_cvt(c[j]); h[j] = hb[j]; }
#pragma unroll
    for (int j = 0; j < 8; j++) c[j] = c[j] - bf2f(hb[j]);
#pragma unroll
    for (int j = 0; j < 8; j++) l[j] = f2bf_cvt(c[j]);
}

// ---------------- batched weight transpose + hi/lo convert: W[K][N] -> Wt[N][K] ----------------
__global__ __launch_bounds__(256)
void wconv4(const float* __restrict__ W0, const float* __restrict__ W1,
            const float* __restrict__ W2, const float* __restrict__ W3,
            unsigned short* __restrict__ Tbase) {
    __shared__ float tile[64][65];
    int z = blockIdx.z;
    const float* W = (z == 0) ? W0 : (z == 1) ? W1 : (z == 2) ? W2 : W3;
    const size_t WS = (size_t)DD * DD;
    unsigned short* Th = Tbase + (size_t)z * 2 * WS;
    unsigned short* Tl = Th + WS;
    int t = threadIdx.x;
    int n0 = blockIdx.x * 64, k0 = blockIdx.y * 64;
    int r = t >> 4, c4 = (t & 15) * 4;
#pragma unroll
    for (int rr = 0; rr < 64; rr += 16) {
        float4 v = *(const float4*)&W[(size_t)(k0 + r + rr) * DD + n0 + c4];
        tile[r + rr][c4 + 0] = v.x; tile[r + rr][c4 + 1] = v.y;
        tile[r + rr][c4 + 2] = v.z; tile[r + rr][c4 + 3] = v.w;
    }
    __syncthreads();
    int rn = t >> 2, kg = (t & 3) * 16;
    u16x8 oh[2], ol[2];
#pragma unroll
    for (int j = 0; j < 16; j++) {
        float x = tile[kg + j][rn];
        unsigned short hb = f2bf(x);
        oh[j >> 3][j & 7] = hb;
        ol[j >> 3][j & 7] = f2bf(x - bf2f(hb));
    }
    size_t o = (size_t)(n0 + rn) * DD + k0 + kg;
    *(u16x8*)&Th[o] = oh[0]; *(u16x8*)&Th[o + 8] = oh[1];
    *(u16x8*)&Tl[o] = ol[0]; *(u16x8*)&Tl[o + 8] = ol[1];
}

// ---------------- split-bf16 MFMA GEMM body: C = A @ Wt^T + bias ----------------
// R6-proven: LDS XOR-swizzle (both sides), distance-1 prefetch after barrier, B loads
// issued before A (A splits while B flies). AFP32=1: A staged from fp32 with in-register
// hi/lo split (HW bf16 converter). AFP32=0: A pre-split bf16 hi/lo (pure-load path —
// fastest GEMM variant measured, R4: 121us).
template<int AFP32>
__device__ __forceinline__
void gemm_body(const float* __restrict__ Af,
               const unsigned short* __restrict__ Ah, const unsigned short* __restrict__ Al,
               const unsigned short* __restrict__ Bh, const unsigned short* __restrict__ Bl,
               const float* __restrict__ bias, float* __restrict__ C,
               unsigned short* __restrict__ Ch, unsigned short* __restrict__ Cl,
               int m0, int n0) {
    __shared__ unsigned short sAh[128 * 32];
    __shared__ unsigned short sAl[128 * 32];
    __shared__ unsigned short sBh[128 * 32];
    __shared__ unsigned short sBl[128 * 32];
    int t = threadIdx.x;
    int lane = t & 63, w = t >> 6;
    int wm = w >> 1, wn = w & 1;
    int lm = lane & 15, quad = lane >> 4;
    int srow = t >> 1, sk = (t & 1) * 16;

    const float* gAf = AFP32 ? (Af + (size_t)(m0 + srow) * DD + sk) : nullptr;
    const unsigned short* gAh = AFP32 ? nullptr : (Ah + (size_t)(m0 + srow) * DD + sk);
    const unsigned short* gAl = AFP32 ? nullptr : (Al + (size_t)(m0 + srow) * DD + sk);
    const unsigned short* gBh = Bh + (size_t)(n0 + srow) * DD + sk;
    const unsigned short* gBl = Bl + (size_t)(n0 + srow) * DD + sk;
    // swizzled LDS write offsets for this thread's two 8-ushort slots
    int f = (srow >> 1) & 3;
    int s0 = (t & 1) * 2;
    int ws0 = srow * 32 + ((s0 ^ f) * 8);
    int ws1 = srow * 32 + (((s0 | 1) ^ f) * 8);

    floatx4 acc[4][4] = {};
    u16x8 a0, a1, a2, a3, b0, b1, b2, b3;
    // prologue: load kt=0 (B first — no VALU dependency; A splits while B flies)
    b0 = *(const u16x8*)(gBh);     b1 = *(const u16x8*)(gBh + 8);
    b2 = *(const u16x8*)(gBl);     b3 = *(const u16x8*)(gBl + 8);
    if (AFP32) {
        float4 f0 = *(const float4*)(gAf);
        float4 f1 = *(const float4*)(gAf + 4);
        float4 f2 = *(const float4*)(gAf + 8);
        float4 f3 = *(const float4*)(gAf + 12);
        split8(f0, f1, a0, a2);
        split8(f2, f3, a1, a3);
    } else {
        a0 = *(const u16x8*)(gAh);     a1 = *(const u16x8*)(gAh + 8);
        a2 = *(const u16x8*)(gAl);     a3 = *(const u16x8*)(gAl + 8);
    }

    for (int kt = 0; kt < 32; kt++) {
        __syncthreads();           // readers of previous tile done
        *(u16x8*)&sAh[ws0] = a0; *(u16x8*)&sAh[ws1] = a1;
        *(u16x8*)&sAl[ws0] = a2; *(u16x8*)&sAl[ws1] = a3;
        *(u16x8*)&sBh[ws0] = b0; *(u16x8*)&sBh[ws1] = b1;
        *(u16x8*)&sBl[ws0] = b2; *(u16x8*)&sBl[ws1] = b3;
        __syncthreads();
        if (kt < 31) {             // prefetch next tile; lands during MFMA below
            int kb = (kt + 1) * 32;
            b0 = *(const u16x8*)(gBh + kb); b1 = *(const u16x8*)(gBh + kb + 8);
            b2 = *(const u16x8*)(gBl + kb); b3 = *(const u16x8*)(gBl + kb + 8);
            if (AFP32) {
                float4 f0 = *(const float4*)(gAf + kb);
                float4 f1 = *(const float4*)(gAf + kb + 4);
                float4 f2 = *(const float4*)(gAf + kb + 8);
                float4 f3 = *(const float4*)(gAf + kb + 12);
                split8(f0, f1, a0, a2);
                split8(f2, f3, a1, a3);
            } else {
                a0 = *(const u16x8*)(gAh + kb); a1 = *(const u16x8*)(gAh + kb + 8);
                a2 = *(const u16x8*)(gAl + kb); a3 = *(const u16x8*)(gAl + kb + 8);
            }
        }

        short8 bhf[4], blf[4];
#pragma unroll
        for (int j = 0; j < 4; j++) {
            int nrow = wn * 64 + j * 16 + lm;
            int nb = nrow * 32 + ((quad ^ ((nrow >> 1) & 3)) * 8);
            bhf[j] = *(const short8*)&sBh[nb];
            blf[j] = *(const short8*)&sBl[nb];
        }
#pragma unroll
        for (int i = 0; i < 4; i++) {
            int arow = wm * 64 + i * 16 + lm;
            int ab = arow * 32 + ((quad ^ ((arow >> 1) & 3)) * 8);
            short8 ah = *(const short8*)&sAh[ab];
            short8 al = *(const short8*)&sAl[ab];
#pragma unroll
            for (int j = 0; j < 4; j++) {
                acc[i][j] = __builtin_amdgcn_mfma_f32_16x16x32_bf16(ah, bhf[j], acc[i][j], 0, 0, 0);
                acc[i][j] = __builtin_amdgcn_mfma_f32_16x16x32_bf16(ah, blf[j], acc[i][j], 0, 0, 0);
                acc[i][j] = __builtin_amdgcn_mfma_f32_16x16x32_bf16(al, bhf[j], acc[i][j], 0, 0, 0);
            }
        }
    }
#pragma unroll
    for (int i = 0; i < 4; i++) {
#pragma unroll
        for (int j = 0; j < 4; j++) {
            int n = n0 + wn * 64 + j * 16 + lm;
            float bv = bias[n];
#pragma unroll
            for (int r = 0; r < 4; r++) {
                int m = m0 + wm * 64 + i * 16 + quad * 4 + r;
                size_t idx = (size_t)m * DD + n;
                float val = acc[i][j][r] + bv;
                if (C) C[idx] = val;
                if (Ch) {
                    unsigned short hb = f2bf_cvt(val);
                    Ch[idx] = hb;
                    Cl[idx] = f2bf_cvt(val - bf2f(hb));
                }
            }
        }
    }
}

// final Wo GEMM: 256 blocks, XCD-pinned; A = pre-split ctx hi/lo bf16 (written by attn3
// epilogue) — pure-load A path, no split VALU on this 1-wave/SIMD kernel's critical path
__global__ __launch_bounds__(256)
void mfma_gemm_bias(const unsigned short* __restrict__ Ah, const unsigned short* __restrict__ Al,
                    const unsigned short* __restrict__ Bh, const unsigned short* __restrict__ Bl,
                    const float* __restrict__ bias, float* __restrict__ C) {
    int id = blockIdx.x;
    int xcd = id & 7, s = id >> 3;       // s in 0..31
    int y = xcd * 4 + (s >> 3);          // m-tile 0..31
    int x = s & 7;                       // n-tile 0..7
    gemm_body<0>(nullptr, Ah, Al, Bh, Bl, bias, C, nullptr, nullptr, y * 128, x * 128);
}

// batched q/k/v GEMM: 768 blocks linear; XCD-bijective decode; A = raw fp32 inputs
__global__ __launch_bounds__(256)
void mfma_gemm_qkv(const float* __restrict__ qin, const float* __restrict__ kin,
                   const float* __restrict__ vin, const unsigned short* __restrict__ wbase,
                   const float* __restrict__ bq, const float* __restrict__ bk,
                   const float* __restrict__ bv, float* __restrict__ Cq,
                   unsigned short* __restrict__ obase) {
    int id = blockIdx.x;
    int xcd = id & 7, s = id >> 3;       // s in 0..95
    int p = xcd * 12 + (s >> 3);         // (z,y) pair 0..95
    int x = s & 7;
    int z = p >> 5;                      // 0..2
    int y = p & 31;
    const size_t NB = (size_t)BB * LL * DD;
    const size_t WS = (size_t)DD * DD;
    const float* Af = (z == 0) ? qin : (z == 1) ? kin : vin;
    const unsigned short* Bh = wbase + (size_t)z * 2 * WS;
    const float* bias = (z == 0) ? bq : (z == 1) ? bk : bv;
    float* C = (z == 0) ? Cq : nullptr;
    unsigned short* Ch = obase + (size_t)z * 2 * NB;
    gemm_body<1>(Af, nullptr, nullptr, Bh, Bh + WS, bias, C, Ch, Ch + NB, y * 128, x * 128);
}

// ---------------- batched V transpose to Vt[d][l] (bf16 hi+lo in one launch) ----------------
__global__ __launch_bounds__(256)
void vt_prep2(const unsigned short* __restrict__ voh, const unsigned short* __restrict__ vol,
              unsigned short* __restrict__ vth, unsigned short* __restrict__ vtl) {
    __shared__ unsigned short tile[128 * 68];
    int t = threadIdx.x;
    int which = blockIdx.x & 1;
    int l0 = (blockIdx.x >> 1) * 128, h = blockIdx.y, b = blockIdx.z;
    const unsigned short* src = which ? vol : voh;
    unsigned short* dst = which ? vtl : vth;
#pragma unroll
    for (int i = 0; i < 8; i++) {
        int u = t + i * 256;                 // ushort4 units
        int l = u >> 4, c4 = (u & 15) * 4;
        u16x4 v4 = *(const u16x4*)&src[((size_t)(b * LL + l0 + l)) * DD + h * DK + c4];
        tile[l * 68 + c4 + 0] = v4[0]; tile[l * 68 + c4 + 1] = v4[1];
        tile[l * 68 + c4 + 2] = v4[2]; tile[l * 68 + c4 + 3] = v4[3];
    }
    __syncthreads();
    size_t ob = ((size_t)(b * HH + h)) * DK * LL;
#pragma unroll
    for (int i = 0; i < 8; i++) {
        int u = t + i * 256;                 // ushort4 units along l
        int d = u >> 5, lq = (u & 31) * 4;
        u16x4 o;
#pragma unroll
        for (int j = 0; j < 4; j++) o[j] = tile[(lq + j) * 68 + d];
        *(u16x4*)&dst[ob + (size_t)d * LL + l0 + lq] = o;
    }
}

// ---------------- alv = (A @ Wp + bias) transposed to (B,H,L) ----------------
__global__ __launch_bounds__(256)
void alv_gemm(const float* __restrict__ A, const float* __restrict__ Wp,
              const float* __restrict__ bias, float* __restrict__ alv) {
    __shared__ float As[16][65];
    __shared__ float Ws[64][17];
    int t = threadIdx.x;
    int m0 = blockIdx.x * 16;
    int r = t >> 4, hh = t & 15;
    float acc = 0.f;
    for (int kt = 0; kt < 16; kt++) {
        __syncthreads();
#pragma unroll
        for (int i = 0; i < 4; i++) {
            int e = t + i * 256;
            int rr = e >> 6, kk = e & 63;
            As[rr][kk] = A[(size_t)(m0 + rr) * DD + kt * 64 + kk];
        }
#pragma unroll
        for (int i = 0; i < 4; i++) {
            int e = t + i * 256;
            int kk = e >> 4, h2 = e & 15;
            Ws[kk][h2] = Wp[(size_t)(kt * 64 + kk) * HH + h2];
        }
        __syncthreads();
#pragma unroll
        for (int kk = 0; kk < 64; kk++) acc += As[r][kk] * Ws[kk][hh];
    }
    int m = m0 + r;
    int b = m >> 9, l = m & 511;
    alv[(size_t)(b * HH + hh) * LL + l] = acc + bias[hh];
}

// ---------------- clustering ----------------
__global__ __launch_bounds__(256)
void cluster_kernel(const float* __restrict__ zsrc, const float* __restrict__ alv,
                    const float* __restrict__ mu, const float* __restrict__ logvar,
                    const float* __restrict__ logprior,
                    float* __restrict__ cp_out, float* __restrict__ lpdf_out,
                    unsigned int* __restrict__ maxenc, float* __restrict__ kl_out,
                    int isHead) {
    __shared__ float s_mu[CC * DK], s_iv[CC * DK], s_lv[CC * DK];
    __shared__ float s_slv[CC], s_siv[CC], s_lp[CC];
    __shared__ float s_red[256];
    int t = threadIdx.x;
    int tile = blockIdx.x & 1;
    int bh = blockIdx.x >> 1;
    int h = bh & (HH - 1), b = bh >> 4;
    int hm = isHead ? 0 : h;

    {
        float m = mu[hm * CC * DK + t];
        float lv = logvar[hm * CC * DK + t];
        s_mu[t] = m; s_lv[t] = lv; s_iv[t] = expf(-lv);
    }
    __syncthreads();
    if (t < CC) {
        float slv = 0.f, siv = 0.f;
        for (int d = 0; d < DK; d++) { slv += s_lv[t * DK + d]; siv += s_iv[t * DK + d]; }
        s_slv[t] = slv; s_siv[t] = siv;
    }
    if (t == CC) {
        float x[CC];
        float m = -1e30f;
        for (int c = 0; c < CC; c++) { x[c] = logprior[hm * CC + c]; m = fmaxf(m, x[c]); }
        float se = 0.f;
        for (int c = 0; c < CC; c++) se += expf(x[c] - m);
        float lse = m + logf(se);
        for (int c = 0; c < CC; c++) s_lp[c] = x[c] - lse;
    }
    __syncthreads();

    int l = tile * 256 + t;
    const float* zp = zsrc + ((size_t)(b * LL + l)) * DD + h * DK;
    float acc[CC] = {0.f, 0.f, 0.f, 0.f};
    for (int d = 0; d < DK; d += 4) {
        float4 z4 = *(const float4*)(zp + d);
#pragma unroll
        for (int c = 0; c < CC; c++) {
            float d0 = z4.x - s_mu[c * DK + d];     acc[c] += d0 * d0 * s_iv[c * DK + d];
            float d1 = z4.y - s_mu[c * DK + d + 1]; acc[c] += d1 * d1 * s_iv[c * DK + d + 1];
            float d2 = z4.z - s_mu[c * DK + d + 2]; acc[c] += d2 * d2 * s_iv[c * DK + d + 2];
            float d3 = z4.w - s_mu[c * DK + d + 3]; acc[c] += d3 * d3 * s_iv[c * DK + d + 3];
        }
    }
    float lpdf[CC];
#pragma unroll
    for (int c = 0; c < CC; c++)
        lpdf[c] = -0.5f * acc[c] - 0.5f * s_slv[c] - NEG_DPI + s_lp[c];
    float m = fmaxf(fmaxf(lpdf[0], lpdf[1]), fmaxf(lpdf[2], lpdf[3]));
    float se = 0.f;
#pragma unroll
    for (int c = 0; c < CC; c++) se += expf(lpdf[c] - m);
    float lse = m + logf(se);
    float lprob[CC], cpv[CC];
    size_t idx = ((size_t)(bh * LL + l)) * CC;
#pragma unroll
    for (int c = 0; c < CC; c++) {
        lprob[c] = lpdf[c] - lse;
        cpv[c] = expf(lprob[c]);
        cp_out[idx + c] = cpv[c];
    }
    if (isHead) {
#pragma unroll
        for (int c = 0; c < CC; c++) lpdf_out[idx + c] = lpdf[c];
    }
    float alvv = alv[(size_t)bh * LL + l];
    float avar = expf(alvv);
    float t1 = 0.f, t2 = 0.f;
#pragma unroll
    for (int c = 0; c < CC; c++) {
        t1 += expf(s_lp[c]) * (s_lp[c] - lprob[c]);
        t2 += cpv[c] * (acc[c] + avar * s_siv[c] + s_slv[c]);
    }
    float klv = t1 + 0.5f * t2 - 0.5f * (float)DK * (1.0f + alvv);
    float tot = block_sum256(klv, s_red);
    if (t == 0) atomicAdd(kl_out + b, tot * (1.0f / (HH * LL)));
    if (isHead) {
        float mt = block_max256(m, s_red);
        if (t == 0) atomicMax(maxenc, fenc(mt));
    }
}

// ---------------- pair stats v2: div loss (+ head: diag log_softmax(aff)) ----------------
__global__ __launch_bounds__(256)
void pairstats_kernel(const float* __restrict__ cp, float* __restrict__ div_out,
                      float* __restrict__ mi_out, int isHead) {
    __shared__ float s_cp[LL * CC];
    __shared__ float s_red[256];
    int t = threadIdx.x;
    int bh = blockIdx.x >> 3;
    int seg = blockIdx.x & 7;
    int b = bh >> 4;
    const float* base = cp + (size_t)bh * LL * CC;
#pragma unroll
    for (int i = 0; i < 2; i++) {
        int e = t + i * 256;               // float4 unit, 512 total
        *(float4*)&s_cp[e * 4] = *(const float4*)&base[e * 4];
    }
    __syncthreads();

    int q = seg * 64 + (t >> 2);
    int ln = t & 3;
    float4 cq = *(float4*)&s_cp[q * 4];
    float divacc = 0.f, m = -1e30f, s = 0.f, selfdot = 0.f;
    for (int k = ln; k < LL; k += 4) {
        float4 ck = *(float4*)&s_cp[k * 4];
        float dot = cq.x * ck.x + cq.y * ck.y + cq.z * ck.z + cq.w * ck.w;
        float del = (k == q) ? 1.f : 0.f;
        float dd = dot - del;
        divacc += dd * dd * (0.75f + 0.5f * del);
        if (isHead) {
            if (dot > m) { s = s * expf(m - dot) + 1.f; m = dot; }
            else         { s += expf(dot - m); }
            if (k == q) selfdot = dot;
        }
    }
#pragma unroll
    for (int off = 1; off <= 2; off <<= 1) divacc += __shfl_xor(divacc, off, 64);
    float diag = 0.f;
    if (isHead) {
#pragma unroll
        for (int off = 1; off <= 2; off <<= 1) {
            float om = __shfl_xor(m, off, 64);
            float os = __shfl_xor(s, off, 64);
            float nm = fmaxf(m, om);
            s = s * expf(m - nm) + os * expf(om - nm);
            m = nm;
        }
#pragma unroll
        for (int off = 1; off <= 2; off <<= 1) selfdot += __shfl_xor(selfdot, off, 64);
        diag = selfdot - (m + logf(s));
    }
    float dtot = block_sum256(ln == 0 ? divacc : 0.f, s_red);
    if (t == 0) atomicAdd(div_out + b, dtot * (1.0f / ((float)HH * LL * LL)));
    if (isHead) {
        float gtot = block_sum256(ln == 0 ? diag : 0.f, s_red);
        if (t == 0) atomicAdd(mi_out + b, -gtot * (1.0f / (HH * LL)));
    }
}

// ---------------- attention: proven one-head-per-block structure ----------------
// Epilogue writes ctxf fp32 AND pre-split cxh/cxl bf16 (R3-proven path) so the Wo GEMM
// takes the pure-load A path.
__global__ __launch_bounds__(256)
void attn3_kernel(const unsigned short* __restrict__ qoh, const unsigned short* __restrict__ qol,
                  const unsigned short* __restrict__ koh, const unsigned short* __restrict__ kol,
                  const unsigned short* __restrict__ vth, const unsigned short* __restrict__ vtl,
                  const float* __restrict__ cpq,
                  float* __restrict__ ctxf, unsigned short* __restrict__ cxh,
                  unsigned short* __restrict__ cxl,
                  float* __restrict__ attn_h, int h0) {
    // union: S fp32 [16][516] (33024 B)  /  Ph,Pl bf16 [16][520] each (33280 B)
    __shared__ __align__(16) char sbuf[33280];
    __shared__ float s_inv[16];
    float* S = (float*)sbuf;
    unsigned short* Ph = (unsigned short*)sbuf;
    unsigned short* Pl = Ph + 16 * 520;

    int t = threadIdx.x;
    // XCD-bijective swizzle: 2048 blocks; combo (b,hl) -> xcd = combo&7
    int id = blockIdx.x;
    int xcd = id & 7;
    int sid = id >> 3;                  // 0..255
    int qt = sid & 31;
    int combo = ((sid >> 5) << 3) | xcd;   // 0..63
    int hl = combo & 7;
    int b = combo >> 3;
    int h = h0 + hl;
    int q0 = qt * 16;
    int lane = t & 63, w = t >> 6;
    int lm = lane & 15, quad = lane >> 4;
    int bh = b * HH + h;

    // ---- phase 1: scores ----
    size_t qbase = ((size_t)(b * LL + q0 + lm)) * DD + h * DK + quad * 8;
    short8 qah0 = *(const short8*)(qoh + qbase);
    short8 qah1 = *(const short8*)(qoh + qbase + 32);
    short8 qal0 = *(const short8*)(qol + qbase);
    short8 qal1 = *(const short8*)(qol + qbase + 32);

    floatx4 sa[8] = {};
#pragma unroll
    for (int j = 0; j < 8; j++) {
        int n0 = w * 128 + j * 16;
        size_t kbase = ((size_t)(b * LL + n0 + lm)) * DD + h * DK + quad * 8;
        short8 kbh0 = *(const short8*)(koh + kbase);
        short8 kbh1 = *(const short8*)(koh + kbase + 32);
        short8 kbl0 = *(const short8*)(kol + kbase);
        short8 kbl1 = *(const short8*)(kol + kbase + 32);
        sa[j] = __builtin_amdgcn_mfma_f32_16x16x32_bf16(qah0, kbh0, sa[j], 0, 0, 0);
        sa[j] = __builtin_amdgcn_mfma_f32_16x16x32_bf16(qah1, kbh1, sa[j], 0, 0, 0);
        sa[j] = __builtin_amdgcn_mfma_f32_16x16x32_bf16(qah0, kbl0, sa[j], 0, 0, 0);
        sa[j] = __builtin_amdgcn_mfma_f32_16x16x32_bf16(qah1, kbl1, sa[j], 0, 0, 0);
        sa[j] = __builtin_amdgcn_mfma_f32_16x16x32_bf16(qal0, kbh0, sa[j], 0, 0, 0);
        sa[j] = __builtin_amdgcn_mfma_f32_16x16x32_bf16(qal1, kbh1, sa[j], 0, 0, 0);
    }
#pragma unroll
    for (int j = 0; j < 8; j++) {
        int kc = w * 128 + j * 16 + lm;
#pragma unroll
        for (int r = 0; r < 4; r++)
            S[(quad * 4 + r) * 516 + kc] = sa[j][r] * 0.125f;
    }
    __syncthreads();

    // ---- phase 2a: softmax + mask + renorm factor (16 lanes per row); cp via L1/L2 ----
    {
        int r = t >> 4, ln = t & 15;
        const float4* cpb = (const float4*)(cpq + (size_t)bh * LL * CC);
        float m = -1e30f;
        for (int k = ln; k < LL; k += 16) m = fmaxf(m, S[r * 516 + k]);
#pragma unroll
        for (int off = 8; off > 0; off >>= 1) m = fmaxf(m, __shfl_xor(m, off, 16));
        float4 cq = cpb[q0 + r];
        float Z = 0.f, Sm = 0.f;
        for (int k = ln; k < LL; k += 16) {
            float e = expf(S[r * 516 + k] - m);
            float4 ck = cpb[k];
            float mask = cq.x * ck.x + cq.y * ck.y + cq.z * ck.z + cq.w * ck.w;
            float a = e * mask;
            Z += e; Sm += a;
            S[r * 516 + k] = a;
        }
#pragma unroll
        for (int off = 8; off > 0; off >>= 1) {
            Z += __shfl_xor(Z, off, 16);
            Sm += __shfl_xor(Sm, off, 16);
        }
        if (ln == 0) s_inv[r] = 1.f / (Sm + 1e-6f * Z);
    }
    __syncthreads();

    // ---- phase 2b: normalize into regs + plain coalesced write of per-head P ----
    float4 pv[8];
#pragma unroll
    for (int i = 0; i < 8; i++) {
        int e = t + i * 256;                 // float4 unit, 2048 total
        int r2 = e >> 7, k4 = (e & 127) * 4;
        float4 p = *(float4*)&S[r2 * 516 + k4];
        float inv = s_inv[r2];
        p.x *= inv; p.y *= inv; p.z *= inv; p.w *= inv;
        pv[i] = p;
        *(float4*)&attn_h[(((size_t)((b * 8 + hl) * LL + q0 + r2)) * LL) + k4] = p;
    }
    __syncthreads();   // all reads of S done; overwrite with Ph/Pl
#pragma unroll
    for (int i = 0; i < 8; i++) {
        int e = t + i * 256;
        int r2 = e >> 7, k4 = (e & 127) * 4;
        float c[4] = {pv[i].x, pv[i].y, pv[i].z, pv[i].w};
        u16x4 hv, lv;
#pragma unroll
        for (int j = 0; j < 4; j++) {
            unsigned short hb = f2bf(c[j]);
            hv[j] = hb;
            lv[j] = f2bf(c[j] - bf2f(hb));
        }
        *(u16x4*)&Ph[r2 * 520 + k4] = hv;
        *(u16x4*)&Pl[r2 * 520 + k4] = lv;
    }
    __syncthreads();

    // ---- phase 3: ctx = P @ V via Vt ----
    int dn = w * 16 + lm;
    const unsigned short* vrh = vth + ((size_t)bh * DK + dn) * LL;
    const unsigned short* vrl = vtl + ((size_t)bh * DK + dn) * LL;
    floatx4 ca = {};
#pragma unroll
    for (int kc = 0; kc < 16; kc++) {
        int kb = kc * 32 + quad * 8;
        short8 pah = *(const short8*)&Ph[lm * 520 + kb];
        short8 pal = *(const short8*)&Pl[lm * 520 + kb];
        short8 vbh = *(const short8*)(vrh + kb);
        short8 vbl = *(const short8*)(vrl + kb);
        ca = __builtin_amdgcn_mfma_f32_16x16x32_bf16(pah, vbh, ca, 0, 0, 0);
        ca = __builtin_amdgcn_mfma_f32_16x16x32_bf16(pah, vbl, ca, 0, 0, 0);
        ca = __builtin_amdgcn_mfma_f32_16x16x32_bf16(pal, vbh, ca, 0, 0, 0);
    }
#pragma unroll
    for (int r = 0; r < 4; r++) {
        float val = ca[r];
        size_t idx = ((size_t)(b * LL + q0 + quad * 4 + r)) * DD + h * DK + dn;
        ctxf[idx] = val;
        unsigned short hb = f2bf(val);
        cxh[idx] = hb;
        cxl[idx] = f2bf(val - bf2f(hb));
    }
}

// ---------------- reduce per-head probs into attn mean (8 heads per pass) ----------------
__global__ __launch_bounds__(256)
void attn_reduce(const float* __restrict__ attn_h, float* __restrict__ attn_out,
                 int accumulate) {
    int e = blockIdx.x * 256 + threadIdx.x;  // float4 unit; total B*L*L/4
    int b = e >> 16;
    int rem = e & 65535;
    float4 s = {0.f, 0.f, 0.f, 0.f};
#pragma unroll
    for (int hl = 0; hl < 8; hl++) {
        float4 v = ((const float4*)attn_h)[(((size_t)(b * 8 + hl)) << 16) + rem];
        s.x += v.x; s.y += v.y; s.z += v.z; s.w += v.w;
    }
    float4* o = (float4*)attn_out + (((size_t)b) << 16) + rem;
    const float sc = 1.0f / (float)HH;
    float4 prev = {0.f, 0.f, 0.f, 0.f};
    if (accumulate) prev = *o;
    prev.x += s.x * sc; prev.y += s.y * sc; prev.z += s.z * sc; prev.w += s.w * sc;
    *o = prev;
}

// ---------------- MI: pdf + wsum ----------------
__global__ __launch_bounds__(256)
void wsum_kernel(const float* __restrict__ lpdf, const float* __restrict__ cp,
                 const unsigned int* __restrict__ maxenc,
                 float* __restrict__ pdf_out, float* __restrict__ wsum_out) {
    __shared__ float s_red[256];
    int t = threadIdx.x;
    int bh = blockIdx.x;
    float M = fdec(*maxenc);
    float a[CC] = {0.f, 0.f, 0.f, 0.f};
    for (int li = 0; li < 2; li++) {
        int l = t + li * 256;
        size_t idx = ((size_t)bh * LL + l) * CC;
        float p0 = expf(lpdf[idx + 0] - M);
        float p1 = expf(lpdf[idx + 1] - M);
        float p2 = expf(lpdf[idx + 2] - M);
        float p3 = expf(lpdf[idx + 3] - M);
        float pd = p0 + p1 + p2 + p3;
        pdf_out[(size_t)bh * LL + l] = pd;
        a[0] += cp[idx + 0] * pd; a[1] += cp[idx + 1] * pd;
        a[2] += cp[idx + 2] * pd; a[3] += cp[idx + 3] * pd;
    }
#pragma unroll
    for (int c = 0; c < CC; c++) {
        float tot = block_sum256(a[c], s_red);
        if (t == 0) wsum_out[bh * CC + c] = tot;
    }
}

// ---------------- MI: pairwise head overlap ----------------
__global__ __launch_bounds__(256)
void mi_kernel(const float* __restrict__ cp, const float* __restrict__ pdf,
               const float* __restrict__ wsum, float* __restrict__ mi_out) {
    __shared__ float s_q[HH * CC];
    __shared__ float s_c[HH * CC];
    __shared__ float s_red[256];
    int t = threadIdx.x;
    int b = blockIdx.x >> 9;
    int l = blockIdx.x & 511;
    if (t < HH * CC) {
        int i = t >> 2, c = t & 3;
        float cpv = cp[((size_t)(b * HH + i) * LL + l) * CC + c];
        s_c[t] = cpv;
        float w = cpv * pdf[(size_t)(b * HH + i) * LL + l];
        float ws = wsum[(b * HH + i) * CC + c];
        s_q[t] = w / fmaxf(ws, 1e-6f);
    }
    __syncthreads();
    int i = t >> 4, j = t & 15;
    float sdot = 0.f;
#pragma unroll
    for (int c = 0; c < CC; c++) sdot += s_q[i * 4 + c] * s_c[j * 4 + c];
    float mi_p = fminf(sdot, 1.f);
    float val = (i != j) ? logf(1.f - mi_p + 1e-6f) : 0.f;
    float tot = block_sum256(val, s_red);
    if (t == 0) atomicAdd(mi_out + b, -10.f * tot * (1.0f / ((float)LL * HH * HH)));
}

// ---------------- launcher ----------------
extern "C" void kernel_launch(void* const* d_in, const int* in_sizes, int n_in,
                              void* d_out, int out_size, void* d_ws, size_t ws_size,
                              hipStream_t stream) {
    (void)in_sizes; (void)n_in; (void)out_size; (void)ws_size;
    const float* query  = (const float*)d_in[0];
    const float* key    = (const float*)d_in[1];
    const float* value  = (const float*)d_in[2];
    const float* Wq     = (const float*)d_in[3];
    const float* bq     = (const float*)d_in[4];
    const float* Wk     = (const float*)d_in[5];
    const float* bk     = (const float*)d_in[6];
    const float* Wv     = (const float*)d_in[7];
    const float* bv     = (const float*)d_in[8];
    const float* Wo     = (const float*)d_in[9];
    const float* bo     = (const float*)d_in[10];
    const float* Wsem   = (const float*)d_in[11];
    const float* bsem   = (const float*)d_in[12];
    const float* Whead  = (const float*)d_in[13];
    const float* bhead  = (const float*)d_in[14];
    const float* tokmu  = (const float*)d_in[15];
    const float* toklv  = (const float*)d_in[16];
    const float* toklp  = (const float*)d_in[17];
    const float* headmu = (const float*)d_in[18];
    const float* headlv = (const float*)d_in[19];
    const float* headlp = (const float*)d_in[20];

    float* ws   = (float*)d_ws;
    const size_t NBLD = (size_t)BB * LL * DD;      // 4194304
    float* q    = ws;                               // fp32 q (cluster/alv need it)
    float* ctxf = ws + NBLD;
    float* alvq = ws + 2 * NBLD;
    float* alvh = alvq + (size_t)BB * HH * LL;
    float* cpq  = alvh + (size_t)BB * HH * LL;
    float* cph  = cpq + (size_t)BB * HH * LL * CC;
    float* lpdfh= cph + (size_t)BB * HH * LL * CC;
    float* pdfb = lpdfh + (size_t)BB * HH * LL * CC;
    float* wsumb= pdfb + (size_t)BB * HH * LL;
    unsigned int* maxenc = (unsigned int*)(wsumb + (size_t)BB * HH * CC);
    float* attn_h = (float*)(maxenc + 4);           // 67 MB region: per-head attn planes

    // bf16 scratch (ushort)
    unsigned short* us = (unsigned short*)(attn_h + (size_t)BB * 8 * LL * LL);
    const size_t WSZ = (size_t)DD * DD;            // 1048576
    unsigned short* qoh = us;                      // [qoh,qol,koh,kol,voh,vol] consecutive
    unsigned short* qol = qoh + NBLD;
    unsigned short* koh = qol + NBLD;
    unsigned short* kol = koh + NBLD;
    unsigned short* voh = kol + NBLD;
    unsigned short* vol = voh + NBLD;
    unsigned short* vth = vol + NBLD;              // Vt[d][l] per (b,h)
    unsigned short* vtl = vth + NBLD;
    unsigned short* wqh = vtl + NBLD;              // [Wq_h,Wq_l,Wk_h,Wk_l,Wv_h,Wv_l,Wo_h,Wo_l]
    unsigned short* woh = wqh + 6 * WSZ;
    unsigned short* wol = woh + WSZ;
    unsigned short* cxh = wol + WSZ;               // ctx hi/lo (attn3 epilogue -> Wo GEMM)
    unsigned short* cxl = cxh + NBLD;

    float* out      = (float*)d_out;
    float* attn_out = out + NBLD;
    float* kl_out   = attn_out + (size_t)BB * LL * LL;
    float* div_out  = kl_out + BB;
    float* mi_out   = div_out + BB;

    hipMemsetAsync(kl_out, 0, 3 * BB * sizeof(float), stream);
    hipMemsetAsync(maxenc, 0, sizeof(unsigned int), stream);

    // all 4 weight transposes in one launch (1024 blocks)
    wconv4<<<dim3(16, 16, 4), 256, 0, stream>>>(Wq, Wk, Wv, Wo, wqh);

    // batched q/k/v GEMM reading raw fp32 inputs (in-register hi/lo split, dist-1 prefetch)
    mfma_gemm_qkv<<<dim3(768), 256, 0, stream>>>(
        query, key, value, wqh, bq, bk, bv, q, qoh);

    // V transpose hi+lo in one launch (1024 blocks)
    vt_prep2<<<dim3(2 * LL / 128, HH, BB), 256, 0, stream>>>(voh, vol, vth, vtl);

    alv_gemm<<<BB * LL / 16, 256, 0, stream>>>(q, Wsem, bsem, alvq);
    cluster_kernel<<<BB * HH * 2, 256, 0, stream>>>(q, alvq, tokmu, toklv, toklp,
                                                    cpq, nullptr, nullptr, kl_out, 0);
    pairstats_kernel<<<BB * HH * 8, 256, 0, stream>>>(cpq, div_out, nullptr, 0);

    // attention: 8 heads per pass; epilogue emits ctx fp32 + hi/lo bf16
    for (int h0 = 0; h0 < HH; h0 += 8) {
        attn3_kernel<<<dim3(2048), 256, 0, stream>>>(
            qoh, qol, koh, kol, vth, vtl, cpq, ctxf, cxh, cxl, attn_h, h0);
        attn_reduce<<<BB * LL * LL / 4 / 256, 256, 0, stream>>>(
            attn_h, attn_out, h0 > 0 ? 1 : 0);
    }

    alv_gemm<<<BB * LL / 16, 256, 0, stream>>>(ctxf, Whead, bhead, alvh);
    cluster_kernel<<<BB * HH * 2, 256, 0, stream>>>(ctxf, alvh, headmu, headlv, headlp,
                                                    cph, lpdfh, maxenc, kl_out, 1);
    pairstats_kernel<<<BB * HH * 8, 256, 0, stream>>>(cph, div_out, mi_out, 1);
    wsum_kernel<<<BB * HH, 256, 0, stream>>>(lpdfh, cph, maxenc, pdfb, wsumb);
    mi_kernel<<<BB * LL, 256, 0, stream>>>(cph, pdfb, wsumb, mi_out);
    mfma_gemm_bias<<<dim3(256), 256, 0, stream>>>(
        cxh, cxl, woh, wol, bo, out);
}

// Round 10
// 731.923 us; speedup vs baseline: 1.0259x; 1.0259x over previous
//
#include <hip/hip_runtime.h>
#include <math.h>

// Problem constants: B=8, L=512, D=1024, H=16, C=4, Dk=64
#define BB 8
#define LL 512
#define DD 1024
#define HH 16
#define CC 4
#define DK 64
#define NEG_DPI 201.06192982974676f   // 64 * pi

typedef __attribute__((ext_vector_type(8))) short short8;     // MFMA A/B frag (8 bf16)
typedef __attribute__((ext_vector_type(4))) float floatx4;    // MFMA C/D frag
typedef __attribute__((ext_vector_type(8))) unsigned short u16x8;
typedef __attribute__((ext_vector_type(4))) unsigned short u16x4;

// ---------------- helpers ----------------
__device__ inline float block_sum256(float v, float* s_red) {
    int t = threadIdx.x;
    s_red[t] = v; __syncthreads();
    for (int off = 128; off > 0; off >>= 1) {
        if (t < off) s_red[t] += s_red[t + off];
        __syncthreads();
    }
    float r = s_red[0]; __syncthreads();
    return r;
}
__device__ inline float block_max256(float v, float* s_red) {
    int t = threadIdx.x;
    s_red[t] = v; __syncthreads();
    for (int off = 128; off > 0; off >>= 1) {
        if (t < off) s_red[t] = fmaxf(s_red[t], s_red[t + off]);
        __syncthreads();
    }
    float r = s_red[0]; __syncthreads();
    return r;
}
__device__ inline unsigned int fenc(float f) {
    unsigned int b = __float_as_uint(f);
    return (b & 0x80000000u) ? ~b : (b | 0x80000000u);
}
__device__ inline float fdec(unsigned int u) {
    return (u & 0x80000000u) ? __uint_as_float(u ^ 0x80000000u) : __uint_as_float(~u);
}
__device__ inline unsigned short f2bf(float x) {   // RNE fp32 -> bf16 (bit-twiddle)
    unsigned int u = __float_as_uint(x);
    return (unsigned short)((u + 0x7FFFu + ((u >> 16) & 1u)) >> 16);
}
// RNE fp32 -> bf16 via hardware converter; bit-identical to f2bf for finite inputs.
__device__ inline unsigned short f2bf_cvt(float x) {
    __bf16 b = (__bf16)x;
    return __builtin_bit_cast(unsigned short, b);
}
__device__ inline float bf2f(unsigned short h) {
    return __uint_as_float((unsigned int)h << 16);
}
// split 8 fp32 (two float4) into hi/lo bf16 octets — hi converts grouped (pk-packable),
// then residuals, then lo converts grouped.
__device__ inline void split8(const float4 x, const float4 y, u16x8& h, u16x8& l) {
    float c[8] = {x.x, x.y, x.z, x.w, y.x, y.y, y.z, y.w};
    unsigned short hb[8];
#pragma unroll
    for (int j = 0; j < 8; j++) { hb[j] = f2bf_cvt(c[j]); h[j] = hb[j]; }
#pragma unroll
    for (int j = 0; j < 8; j++) c[j] = c[j] - bf2f(hb[j]);
#pragma unroll
    for (int j = 0; j < 8; j++) l[j] = f2bf_cvt(c[j]);
}

// ---------------- batched weight transpose + hi/lo convert: W[K][N] -> Wt[N][K] ----------------
__global__ __launch_bounds__(256)
void wconv4(const float* __restrict__ W0, const float* __restrict__ W1,
            const float* __restrict__ W2, const float* __restrict__ W3,
            unsigned short* __restrict__ Tbase) {
    __shared__ float tile[64][65];
    int z = blockIdx.z;
    const float* W = (z == 0) ? W0 : (z == 1) ? W1 : (z == 2) ? W2 : W3;
    const size_t WS = (size_t)DD * DD;
    unsigned short* Th = Tbase + (size_t)z * 2 * WS;
    unsigned short* Tl = Th + WS;
    int t = threadIdx.x;
    int n0 = blockIdx.x * 64, k0 = blockIdx.y * 64;
    int r = t >> 4, c4 = (t & 15) * 4;
#pragma unroll
    for (int rr = 0; rr < 64; rr += 16) {
        float4 v = *(const float4*)&W[(size_t)(k0 + r + rr) * DD + n0 + c4];
        tile[r + rr][c4 + 0] = v.x; tile[r + rr][c4 + 1] = v.y;
        tile[r + rr][c4 + 2] = v.z; tile[r + rr][c4 + 3] = v.w;
    }
    __syncthreads();
    int rn = t >> 2, kg = (t & 3) * 16;
    u16x8 oh[2], ol[2];
#pragma unroll
    for (int j = 0; j < 16; j++) {
        float x = tile[kg + j][rn];
        unsigned short hb = f2bf(x);
        oh[j >> 3][j & 7] = hb;
        ol[j >> 3][j & 7] = f2bf(x - bf2f(hb));
    }
    size_t o = (size_t)(n0 + rn) * DD + k0 + kg;
    *(u16x8*)&Th[o] = oh[0]; *(u16x8*)&Th[o + 8] = oh[1];
    *(u16x8*)&Tl[o] = ol[0]; *(u16x8*)&Tl[o + 8] = ol[1];
}

// ---------------- split-bf16 MFMA GEMM body: C = A @ Wt^T + bias ----------------
// R6-proven: LDS XOR-swizzle (both sides), distance-1 prefetch after barrier, B loads
// issued before A (A splits while B flies). AFP32=1: A staged from fp32 with in-register
// hi/lo split (HW bf16 converter). AFP32=0: A pre-split bf16 hi/lo (pure-load path).
template<int AFP32>
__device__ __forceinline__
void gemm_body(const float* __restrict__ Af,
               const unsigned short* __restrict__ Ah, const unsigned short* __restrict__ Al,
               const unsigned short* __restrict__ Bh, const unsigned short* __restrict__ Bl,
               const float* __restrict__ bias, float* __restrict__ C,
               unsigned short* __restrict__ Ch, unsigned short* __restrict__ Cl,
               int m0, int n0) {
    __shared__ unsigned short sAh[128 * 32];
    __shared__ unsigned short sAl[128 * 32];
    __shared__ unsigned short sBh[128 * 32];
    __shared__ unsigned short sBl[128 * 32];
    int t = threadIdx.x;
    int lane = t & 63, w = t >> 6;
    int wm = w >> 1, wn = w & 1;
    int lm = lane & 15, quad = lane >> 4;
    int srow = t >> 1, sk = (t & 1) * 16;

    const float* gAf = AFP32 ? (Af + (size_t)(m0 + srow) * DD + sk) : nullptr;
    const unsigned short* gAh = AFP32 ? nullptr : (Ah + (size_t)(m0 + srow) * DD + sk);
    const unsigned short* gAl = AFP32 ? nullptr : (Al + (size_t)(m0 + srow) * DD + sk);
    const unsigned short* gBh = Bh + (size_t)(n0 + srow) * DD + sk;
    const unsigned short* gBl = Bl + (size_t)(n0 + srow) * DD + sk;
    // swizzled LDS write offsets for this thread's two 8-ushort slots
    int f = (srow >> 1) & 3;
    int s0 = (t & 1) * 2;
    int ws0 = srow * 32 + ((s0 ^ f) * 8);
    int ws1 = srow * 32 + (((s0 | 1) ^ f) * 8);

    floatx4 acc[4][4] = {};
    u16x8 a0, a1, a2, a3, b0, b1, b2, b3;
    // prologue: load kt=0 (B first — no VALU dependency; A splits while B flies)
    b0 = *(const u16x8*)(gBh);     b1 = *(const u16x8*)(gBh + 8);
    b2 = *(const u16x8*)(gBl);     b3 = *(const u16x8*)(gBl + 8);
    if (AFP32) {
        float4 f0 = *(const float4*)(gAf);
        float4 f1 = *(const float4*)(gAf + 4);
        float4 f2 = *(const float4*)(gAf + 8);
        float4 f3 = *(const float4*)(gAf + 12);
        split8(f0, f1, a0, a2);
        split8(f2, f3, a1, a3);
    } else {
        a0 = *(const u16x8*)(gAh);     a1 = *(const u16x8*)(gAh + 8);
        a2 = *(const u16x8*)(gAl);     a3 = *(const u16x8*)(gAl + 8);
    }

    for (int kt = 0; kt < 32; kt++) {
        __syncthreads();           // readers of previous tile done
        *(u16x8*)&sAh[ws0] = a0; *(u16x8*)&sAh[ws1] = a1;
        *(u16x8*)&sAl[ws0] = a2; *(u16x8*)&sAl[ws1] = a3;
        *(u16x8*)&sBh[ws0] = b0; *(u16x8*)&sBh[ws1] = b1;
        *(u16x8*)&sBl[ws0] = b2; *(u16x8*)&sBl[ws1] = b3;
        __syncthreads();
        if (kt < 31) {             // prefetch next tile; lands during MFMA below
            int kb = (kt + 1) * 32;
            b0 = *(const u16x8*)(gBh + kb); b1 = *(const u16x8*)(gBh + kb + 8);
            b2 = *(const u16x8*)(gBl + kb); b3 = *(const u16x8*)(gBl + kb + 8);
            if (AFP32) {
                float4 f0 = *(const float4*)(gAf + kb);
                float4 f1 = *(const float4*)(gAf + kb + 4);
                float4 f2 = *(const float4*)(gAf + kb + 8);
                float4 f3 = *(const float4*)(gAf + kb + 12);
                split8(f0, f1, a0, a2);
                split8(f2, f3, a1, a3);
            } else {
                a0 = *(const u16x8*)(gAh + kb); a1 = *(const u16x8*)(gAh + kb + 8);
                a2 = *(const u16x8*)(gAl + kb); a3 = *(const u16x8*)(gAl + kb + 8);
            }
        }

        short8 bhf[4], blf[4];
#pragma unroll
        for (int j = 0; j < 4; j++) {
            int nrow = wn * 64 + j * 16 + lm;
            int nb = nrow * 32 + ((quad ^ ((nrow >> 1) & 3)) * 8);
            bhf[j] = *(const short8*)&sBh[nb];
            blf[j] = *(const short8*)&sBl[nb];
        }
#pragma unroll
        for (int i = 0; i < 4; i++) {
            int arow = wm * 64 + i * 16 + lm;
            int ab = arow * 32 + ((quad ^ ((arow >> 1) & 3)) * 8);
            short8 ah = *(const short8*)&sAh[ab];
            short8 al = *(const short8*)&sAl[ab];
#pragma unroll
            for (int j = 0; j < 4; j++) {
                acc[i][j] = __builtin_amdgcn_mfma_f32_16x16x32_bf16(ah, bhf[j], acc[i][j], 0, 0, 0);
                acc[i][j] = __builtin_amdgcn_mfma_f32_16x16x32_bf16(ah, blf[j], acc[i][j], 0, 0, 0);
                acc[i][j] = __builtin_amdgcn_mfma_f32_16x16x32_bf16(al, bhf[j], acc[i][j], 0, 0, 0);
            }
        }
    }
#pragma unroll
    for (int i = 0; i < 4; i++) {
#pragma unroll
        for (int j = 0; j < 4; j++) {
            int n = n0 + wn * 64 + j * 16 + lm;
            float bv = bias[n];
#pragma unroll
            for (int r = 0; r < 4; r++) {
                int m = m0 + wm * 64 + i * 16 + quad * 4 + r;
                size_t idx = (size_t)m * DD + n;
                float val = acc[i][j][r] + bv;
                if (C) C[idx] = val;
                if (Ch) {
                    unsigned short hb = f2bf_cvt(val);
                    Ch[idx] = hb;
                    Cl[idx] = f2bf_cvt(val - bf2f(hb));
                }
            }
        }
    }
}

// final Wo GEMM: 256 blocks, XCD-pinned; A = pre-split ctx hi/lo bf16 (attn3 epilogue)
__global__ __launch_bounds__(256)
void mfma_gemm_bias(const unsigned short* __restrict__ Ah, const unsigned short* __restrict__ Al,
                    const unsigned short* __restrict__ Bh, const unsigned short* __restrict__ Bl,
                    const float* __restrict__ bias, float* __restrict__ C) {
    int id = blockIdx.x;
    int xcd = id & 7, s = id >> 3;       // s in 0..31
    int y = xcd * 4 + (s >> 3);          // m-tile 0..31
    int x = s & 7;                       // n-tile 0..7
    gemm_body<0>(nullptr, Ah, Al, Bh, Bl, bias, C, nullptr, nullptr, y * 128, x * 128);
}

// batched q/k/v GEMM: 768 blocks linear; XCD-bijective decode; A = raw fp32 inputs
__global__ __launch_bounds__(256)
void mfma_gemm_qkv(const float* __restrict__ qin, const float* __restrict__ kin,
                   const float* __restrict__ vin, const unsigned short* __restrict__ wbase,
                   const float* __restrict__ bq, const float* __restrict__ bk,
                   const float* __restrict__ bv, float* __restrict__ Cq,
                   unsigned short* __restrict__ obase) {
    int id = blockIdx.x;
    int xcd = id & 7, s = id >> 3;       // s in 0..95
    int p = xcd * 12 + (s >> 3);         // (z,y) pair 0..95
    int x = s & 7;
    int z = p >> 5;                      // 0..2
    int y = p & 31;
    const size_t NB = (size_t)BB * LL * DD;
    const size_t WS = (size_t)DD * DD;
    const float* Af = (z == 0) ? qin : (z == 1) ? kin : vin;
    const unsigned short* Bh = wbase + (size_t)z * 2 * WS;
    const float* bias = (z == 0) ? bq : (z == 1) ? bk : bv;
    float* C = (z == 0) ? Cq : nullptr;
    unsigned short* Ch = obase + (size_t)z * 2 * NB;
    gemm_body<1>(Af, nullptr, nullptr, Bh, Bh + WS, bias, C, Ch, Ch + NB, y * 128, x * 128);
}

// ---------------- batched V transpose to Vt[d][l] (bf16 hi+lo in one launch) ----------------
__global__ __launch_bounds__(256)
void vt_prep2(const unsigned short* __restrict__ voh, const unsigned short* __restrict__ vol,
              unsigned short* __restrict__ vth, unsigned short* __restrict__ vtl) {
    __shared__ unsigned short tile[128 * 68];
    int t = threadIdx.x;
    int which = blockIdx.x & 1;
    int l0 = (blockIdx.x >> 1) * 128, h = blockIdx.y, b = blockIdx.z;
    const unsigned short* src = which ? vol : voh;
    unsigned short* dst = which ? vtl : vth;
#pragma unroll
    for (int i = 0; i < 8; i++) {
        int u = t + i * 256;                 // ushort4 units
        int l = u >> 4, c4 = (u & 15) * 4;
        u16x4 v4 = *(const u16x4*)&src[((size_t)(b * LL + l0 + l)) * DD + h * DK + c4];
        tile[l * 68 + c4 + 0] = v4[0]; tile[l * 68 + c4 + 1] = v4[1];
        tile[l * 68 + c4 + 2] = v4[2]; tile[l * 68 + c4 + 3] = v4[3];
    }
    __syncthreads();
    size_t ob = ((size_t)(b * HH + h)) * DK * LL;
#pragma unroll
    for (int i = 0; i < 8; i++) {
        int u = t + i * 256;                 // ushort4 units along l
        int d = u >> 5, lq = (u & 31) * 4;
        u16x4 o;
#pragma unroll
        for (int j = 0; j < 4; j++) o[j] = tile[(lq + j) * 68 + d];
        *(u16x4*)&dst[ob + (size_t)d * LL + l0 + lq] = o;
    }
}

// ---------------- alv = (A @ Wp + bias) transposed to (B,H,L) ----------------
__global__ __launch_bounds__(256)
void alv_gemm(const float* __restrict__ A, const float* __restrict__ Wp,
              const float* __restrict__ bias, float* __restrict__ alv) {
    __shared__ float As[16][65];
    __shared__ float Ws[64][17];
    int t = threadIdx.x;
    int m0 = blockIdx.x * 16;
    int r = t >> 4, hh = t & 15;
    float acc = 0.f;
    for (int kt = 0; kt < 16; kt++) {
        __syncthreads();
#pragma unroll
        for (int i = 0; i < 4; i++) {
            int e = t + i * 256;
            int rr = e >> 6, kk = e & 63;
            As[rr][kk] = A[(size_t)(m0 + rr) * DD + kt * 64 + kk];
        }
#pragma unroll
        for (int i = 0; i < 4; i++) {
            int e = t + i * 256;
            int kk = e >> 4, h2 = e & 15;
            Ws[kk][h2] = Wp[(size_t)(kt * 64 + kk) * HH + h2];
        }
        __syncthreads();
#pragma unroll
        for (int kk = 0; kk < 64; kk++) acc += As[r][kk] * Ws[kk][hh];
    }
    int m = m0 + r;
    int b = m >> 9, l = m & 511;
    alv[(size_t)(b * HH + hh) * LL + l] = acc + bias[hh];
}

// ---------------- clustering ----------------
__global__ __launch_bounds__(256)
void cluster_kernel(const float* __restrict__ zsrc, const float* __restrict__ alv,
                    const float* __restrict__ mu, const float* __restrict__ logvar,
                    const float* __restrict__ logprior,
                    float* __restrict__ cp_out, float* __restrict__ lpdf_out,
                    unsigned int* __restrict__ maxenc, float* __restrict__ kl_out,
                    int isHead) {
    __shared__ float s_mu[CC * DK], s_iv[CC * DK], s_lv[CC * DK];
    __shared__ float s_slv[CC], s_siv[CC], s_lp[CC];
    __shared__ float s_red[256];
    int t = threadIdx.x;
    int tile = blockIdx.x & 1;
    int bh = blockIdx.x >> 1;
    int h = bh & (HH - 1), b = bh >> 4;
    int hm = isHead ? 0 : h;

    {
        float m = mu[hm * CC * DK + t];
        float lv = logvar[hm * CC * DK + t];
        s_mu[t] = m; s_lv[t] = lv; s_iv[t] = expf(-lv);
    }
    __syncthreads();
    if (t < CC) {
        float slv = 0.f, siv = 0.f;
        for (int d = 0; d < DK; d++) { slv += s_lv[t * DK + d]; siv += s_iv[t * DK + d]; }
        s_slv[t] = slv; s_siv[t] = siv;
    }
    if (t == CC) {
        float x[CC];
        float m = -1e30f;
        for (int c = 0; c < CC; c++) { x[c] = logprior[hm * CC + c]; m = fmaxf(m, x[c]); }
        float se = 0.f;
        for (int c = 0; c < CC; c++) se += expf(x[c] - m);
        float lse = m + logf(se);
        for (int c = 0; c < CC; c++) s_lp[c] = x[c] - lse;
    }
    __syncthreads();

    int l = tile * 256 + t;
    const float* zp = zsrc + ((size_t)(b * LL + l)) * DD + h * DK;
    float acc[CC] = {0.f, 0.f, 0.f, 0.f};
    for (int d = 0; d < DK; d += 4) {
        float4 z4 = *(const float4*)(zp + d);
#pragma unroll
        for (int c = 0; c < CC; c++) {
            float d0 = z4.x - s_mu[c * DK + d];     acc[c] += d0 * d0 * s_iv[c * DK + d];
            float d1 = z4.y - s_mu[c * DK + d + 1]; acc[c] += d1 * d1 * s_iv[c * DK + d + 1];
            float d2 = z4.z - s_mu[c * DK + d + 2]; acc[c] += d2 * d2 * s_iv[c * DK + d + 2];
            float d3 = z4.w - s_mu[c * DK + d + 3]; acc[c] += d3 * d3 * s_iv[c * DK + d + 3];
        }
    }
    float lpdf[CC];
#pragma unroll
    for (int c = 0; c < CC; c++)
        lpdf[c] = -0.5f * acc[c] - 0.5f * s_slv[c] - NEG_DPI + s_lp[c];
    float m = fmaxf(fmaxf(lpdf[0], lpdf[1]), fmaxf(lpdf[2], lpdf[3]));
    float se = 0.f;
#pragma unroll
    for (int c = 0; c < CC; c++) se += expf(lpdf[c] - m);
    float lse = m + logf(se);
    float lprob[CC], cpv[CC];
    size_t idx = ((size_t)(bh * LL + l)) * CC;
#pragma unroll
    for (int c = 0; c < CC; c++) {
        lprob[c] = lpdf[c] - lse;
        cpv[c] = expf(lprob[c]);
        cp_out[idx + c] = cpv[c];
    }
    if (isHead) {
#pragma unroll
        for (int c = 0; c < CC; c++) lpdf_out[idx + c] = lpdf[c];
    }
    float alvv = alv[(size_t)bh * LL + l];
    float avar = expf(alvv);
    float t1 = 0.f, t2 = 0.f;
#pragma unroll
    for (int c = 0; c < CC; c++) {
        t1 += expf(s_lp[c]) * (s_lp[c] - lprob[c]);
        t2 += cpv[c] * (acc[c] + avar * s_siv[c] + s_slv[c]);
    }
    float klv = t1 + 0.5f * t2 - 0.5f * (float)DK * (1.0f + alvv);
    float tot = block_sum256(klv, s_red);
    if (t == 0) atomicAdd(kl_out + b, tot * (1.0f / (HH * LL)));
    if (isHead) {
        float mt = block_max256(m, s_red);
        if (t == 0) atomicMax(maxenc, fenc(mt));
    }
}

// ---------------- pair stats v2: div loss (+ head: diag log_softmax(aff)) ----------------
__global__ __launch_bounds__(256)
void pairstats_kernel(const float* __restrict__ cp, float* __restrict__ div_out,
                      float* __restrict__ mi_out, int isHead) {
    __shared__ float s_cp[LL * CC];
    __shared__ float s_red[256];
    int t = threadIdx.x;
    int bh = blockIdx.x >> 3;
    int seg = blockIdx.x & 7;
    int b = bh >> 4;
    const float* base = cp + (size_t)bh * LL * CC;
#pragma unroll
    for (int i = 0; i < 2; i++) {
        int e = t + i * 256;               // float4 unit, 512 total
        *(float4*)&s_cp[e * 4] = *(const float4*)&base[e * 4];
    }
    __syncthreads();

    int q = seg * 64 + (t >> 2);
    int ln = t & 3;
    float4 cq = *(float4*)&s_cp[q * 4];
    float divacc = 0.f, m = -1e30f, s = 0.f, selfdot = 0.f;
    for (int k = ln; k < LL; k += 4) {
        float4 ck = *(float4*)&s_cp[k * 4];
        float dot = cq.x * ck.x + cq.y * ck.y + cq.z * ck.z + cq.w * ck.w;
        float del = (k == q) ? 1.f : 0.f;
        float dd = dot - del;
        divacc += dd * dd * (0.75f + 0.5f * del);
        if (isHead) {
            if (dot > m) { s = s * expf(m - dot) + 1.f; m = dot; }
            else         { s += expf(dot - m); }
            if (k == q) selfdot = dot;
        }
    }
#pragma unroll
    for (int off = 1; off <= 2; off <<= 1) divacc += __shfl_xor(divacc, off, 64);
    float diag = 0.f;
    if (isHead) {
#pragma unroll
        for (int off = 1; off <= 2; off <<= 1) {
            float om = __shfl_xor(m, off, 64);
            float os = __shfl_xor(s, off, 64);
            float nm = fmaxf(m, om);
            s = s * expf(m - nm) + os * expf(om - nm);
            m = nm;
        }
#pragma unroll
        for (int off = 1; off <= 2; off <<= 1) selfdot += __shfl_xor(selfdot, off, 64);
        diag = selfdot - (m + logf(s));
    }
    float dtot = block_sum256(ln == 0 ? divacc : 0.f, s_red);
    if (t == 0) atomicAdd(div_out + b, dtot * (1.0f / ((float)HH * LL * LL)));
    if (isHead) {
        float gtot = block_sum256(ln == 0 ? diag : 0.f, s_red);
        if (t == 0) atomicAdd(mi_out + b, -gtot * (1.0f / (HH * LL)));
    }
}

// ---------------- attention: one-head-per-block; s_cp restored to LDS (R0-proven) ----------
// R9 post-mortem: dropping the s_cp LDS stage (R3) made phase-2a issue 32 dependent global
// loads per thread inside the softmax loop (~110us/launch vs R0's 81us with LDS staging).
// Restored here: stage cp rows at block start (overlaps phase-1 MFMA), read mask from LDS.
// LDS 41.5KB -> 3 blocks/CU (R0-proven). Epilogue keeps ctxf + cxh/cxl emission.
__global__ __launch_bounds__(256)
void attn3_kernel(const unsigned short* __restrict__ qoh, const unsigned short* __restrict__ qol,
                  const unsigned short* __restrict__ koh, const unsigned short* __restrict__ kol,
                  const unsigned short* __restrict__ vth, const unsigned short* __restrict__ vtl,
                  const float* __restrict__ cpq,
                  float* __restrict__ ctxf, unsigned short* __restrict__ cxh,
                  unsigned short* __restrict__ cxl,
                  float* __restrict__ attn_h, int h0) {
    // union: S fp32 [16][516] (33024 B)  /  Ph,Pl bf16 [16][520] each (33280 B)
    __shared__ __align__(16) char sbuf[33280];
    __shared__ float s_cp[LL * CC];    // 8 KB
    __shared__ float s_inv[16];
    float* S = (float*)sbuf;
    unsigned short* Ph = (unsigned short*)sbuf;
    unsigned short* Pl = Ph + 16 * 520;

    int t = threadIdx.x;
    // XCD-bijective swizzle: 2048 blocks; combo (b,hl) -> xcd = combo&7
    int id = blockIdx.x;
    int xcd = id & 7;
    int sid = id >> 3;                  // 0..255
    int qt = sid & 31;
    int combo = ((sid >> 5) << 3) | xcd;   // 0..63
    int hl = combo & 7;
    int b = combo >> 3;
    int h = h0 + hl;
    int q0 = qt * 16;
    int lane = t & 63, w = t >> 6;
    int lm = lane & 15, quad = lane >> 4;
    int bh = b * HH + h;

    // stage cp rows for this (b,h) — overlaps with phase-1 MFMA below
    {
        const float* cpb = cpq + (size_t)bh * LL * CC;
#pragma unroll
        for (int i = 0; i < 2; i++) {
            int e = t + i * 256;                  // float4 unit
            *(float4*)&s_cp[e * 4] = *(const float4*)&cpb[e * 4];
        }
    }

    // ---- phase 1: scores ----
    size_t qbase = ((size_t)(b * LL + q0 + lm)) * DD + h * DK + quad * 8;
    short8 qah0 = *(const short8*)(qoh + qbase);
    short8 qah1 = *(const short8*)(qoh + qbase + 32);
    short8 qal0 = *(const short8*)(qol + qbase);
    short8 qal1 = *(const short8*)(qol + qbase + 32);

    floatx4 sa[8] = {};
#pragma unroll
    for (int j = 0; j < 8; j++) {
        int n0 = w * 128 + j * 16;
        size_t kbase = ((size_t)(b * LL + n0 + lm)) * DD + h * DK + quad * 8;
        short8 kbh0 = *(const short8*)(koh + kbase);
        short8 kbh1 = *(const short8*)(koh + kbase + 32);
        short8 kbl0 = *(const short8*)(kol + kbase);
        short8 kbl1 = *(const short8*)(kol + kbase + 32);
        sa[j] = __builtin_amdgcn_mfma_f32_16x16x32_bf16(qah0, kbh0, sa[j], 0, 0, 0);
        sa[j] = __builtin_amdgcn_mfma_f32_16x16x32_bf16(qah1, kbh1, sa[j], 0, 0, 0);
        sa[j] = __builtin_amdgcn_mfma_f32_16x16x32_bf16(qah0, kbl0, sa[j], 0, 0, 0);
        sa[j] = __builtin_amdgcn_mfma_f32_16x16x32_bf16(qah1, kbl1, sa[j], 0, 0, 0);
        sa[j] = __builtin_amdgcn_mfma_f32_16x16x32_bf16(qal0, kbh0, sa[j], 0, 0, 0);
        sa[j] = __builtin_amdgcn_mfma_f32_16x16x32_bf16(qal1, kbh1, sa[j], 0, 0, 0);
    }
#pragma unroll
    for (int j = 0; j < 8; j++) {
        int kc = w * 128 + j * 16 + lm;
#pragma unroll
        for (int r = 0; r < 4; r++)
            S[(quad * 4 + r) * 516 + kc] = sa[j][r] * 0.125f;
    }
    __syncthreads();

    // ---- phase 2a: softmax + mask + renorm factor (16 lanes per row); cp from LDS ----
    {
        int r = t >> 4, ln = t & 15;
        float m = -1e30f;
        for (int k = ln; k < LL; k += 16) m = fmaxf(m, S[r * 516 + k]);
#pragma unroll
        for (int off = 8; off > 0; off >>= 1) m = fmaxf(m, __shfl_xor(m, off, 16));
        float4 cq = *(float4*)&s_cp[(q0 + r) * 4];
        float Z = 0.f, Sm = 0.f;
        for (int k = ln; k < LL; k += 16) {
            float e = expf(S[r * 516 + k] - m);
            float4 ck = *(float4*)&s_cp[k * 4];
            float mask = cq.x * ck.x + cq.y * ck.y + cq.z * ck.z + cq.w * ck.w;
            float a = e * mask;
            Z += e; Sm += a;
            S[r * 516 + k] = a;
        }
#pragma unroll
        for (int off = 8; off > 0; off >>= 1) {
            Z += __shfl_xor(Z, off, 16);
            Sm += __shfl_xor(Sm, off, 16);
        }
        if (ln == 0) s_inv[r] = 1.f / (Sm + 1e-6f * Z);
    }
    __syncthreads();

    // ---- phase 2b: normalize into regs + plain coalesced write of per-head P ----
    float4 pv[8];
#pragma unroll
    for (int i = 0; i < 8; i++) {
        int e = t + i * 256;                 // float4 unit, 2048 total
        int r2 = e >> 7, k4 = (e & 127) * 4;
        float4 p = *(float4*)&S[r2 * 516 + k4];
        float inv = s_inv[r2];
        p.x *= inv; p.y *= inv; p.z *= inv; p.w *= inv;
        pv[i] = p;
        *(float4*)&attn_h[(((size_t)((b * 8 + hl) * LL + q0 + r2)) * LL) + k4] = p;
    }
    __syncthreads();   // all reads of S done; overwrite with Ph/Pl
#pragma unroll
    for (int i = 0; i < 8; i++) {
        int e = t + i * 256;
        int r2 = e >> 7, k4 = (e & 127) * 4;
        float c[4] = {pv[i].x, pv[i].y, pv[i].z, pv[i].w};
        u16x4 hv, lv;
#pragma unroll
        for (int j = 0; j < 4; j++) {
            unsigned short hb = f2bf(c[j]);
            hv[j] = hb;
            lv[j] = f2bf(c[j] - bf2f(hb));
        }
        *(u16x4*)&Ph[r2 * 520 + k4] = hv;
        *(u16x4*)&Pl[r2 * 520 + k4] = lv;
    }
    __syncthreads();

    // ---- phase 3: ctx = P @ V via Vt ----
    int dn = w * 16 + lm;
    const unsigned short* vrh = vth + ((size_t)bh * DK + dn) * LL;
    const unsigned short* vrl = vtl + ((size_t)bh * DK + dn) * LL;
    floatx4 ca = {};
#pragma unroll
    for (int kc = 0; kc < 16; kc++) {
        int kb = kc * 32 + quad * 8;
        short8 pah = *(const short8*)&Ph[lm * 520 + kb];
        short8 pal = *(const short8*)&Pl[lm * 520 + kb];
        short8 vbh = *(const short8*)(vrh + kb);
        short8 vbl = *(const short8*)(vrl + kb);
        ca = __builtin_amdgcn_mfma_f32_16x16x32_bf16(pah, vbh, ca, 0, 0, 0);
        ca = __builtin_amdgcn_mfma_f32_16x16x32_bf16(pah, vbl, ca, 0, 0, 0);
        ca = __builtin_amdgcn_mfma_f32_16x16x32_bf16(pal, vbh, ca, 0, 0, 0);
    }
#pragma unroll
    for (int r = 0; r < 4; r++) {
        float val = ca[r];
        size_t idx = ((size_t)(b * LL + q0 + quad * 4 + r)) * DD + h * DK + dn;
        ctxf[idx] = val;
        unsigned short hb = f2bf(val);
        cxh[idx] = hb;
        cxl[idx] = f2bf(val - bf2f(hb));
    }
}

// ---------------- reduce per-head probs into attn mean (8 heads per pass) ----------------
__global__ __launch_bounds__(256)
void attn_reduce(const float* __restrict__ attn_h, float* __restrict__ attn_out,
                 int accumulate) {
    int e = blockIdx.x * 256 + threadIdx.x;  // float4 unit; total B*L*L/4
    int b = e >> 16;
    int rem = e & 65535;
    float4 s = {0.f, 0.f, 0.f, 0.f};
#pragma unroll
    for (int hl = 0; hl < 8; hl++) {
        float4 v = ((const float4*)attn_h)[(((size_t)(b * 8 + hl)) << 16) + rem];
        s.x += v.x; s.y += v.y; s.z += v.z; s.w += v.w;
    }
    float4* o = (float4*)attn_out + (((size_t)b) << 16) + rem;
    const float sc = 1.0f / (float)HH;
    float4 prev = {0.f, 0.f, 0.f, 0.f};
    if (accumulate) prev = *o;
    prev.x += s.x * sc; prev.y += s.y * sc; prev.z += s.z * sc; prev.w += s.w * sc;
    *o = prev;
}

// ---------------- MI: pdf + wsum ----------------
__global__ __launch_bounds__(256)
void wsum_kernel(const float* __restrict__ lpdf, const float* __restrict__ cp,
                 const unsigned int* __restrict__ maxenc,
                 float* __restrict__ pdf_out, float* __restrict__ wsum_out) {
    __shared__ float s_red[256];
    int t = threadIdx.x;
    int bh = blockIdx.x;
    float M = fdec(*maxenc);
    float a[CC] = {0.f, 0.f, 0.f, 0.f};
    for (int li = 0; li < 2; li++) {
        int l = t + li * 256;
        size_t idx = ((size_t)bh * LL + l) * CC;
        float p0 = expf(lpdf[idx + 0] - M);
        float p1 = expf(lpdf[idx + 1] - M);
        float p2 = expf(lpdf[idx + 2] - M);
        float p3 = expf(lpdf[idx + 3] - M);
        float pd = p0 + p1 + p2 + p3;
        pdf_out[(size_t)bh * LL + l] = pd;
        a[0] += cp[idx + 0] * pd; a[1] += cp[idx + 1] * pd;
        a[2] += cp[idx + 2] * pd; a[3] += cp[idx + 3] * pd;
    }
#pragma unroll
    for (int c = 0; c < CC; c++) {
        float tot = block_sum256(a[c], s_red);
        if (t == 0) wsum_out[bh * CC + c] = tot;
    }
}

// ---------------- MI: pairwise head overlap ----------------
__global__ __launch_bounds__(256)
void mi_kernel(const float* __restrict__ cp, const float* __restrict__ pdf,
               const float* __restrict__ wsum, float* __restrict__ mi_out) {
    __shared__ float s_q[HH * CC];
    __shared__ float s_c[HH * CC];
    __shared__ float s_red[256];
    int t = threadIdx.x;
    int b = blockIdx.x >> 9;
    int l = blockIdx.x & 511;
    if (t < HH * CC) {
        int i = t >> 2, c = t & 3;
        float cpv = cp[((size_t)(b * HH + i) * LL + l) * CC + c];
        s_c[t] = cpv;
        float w = cpv * pdf[(size_t)(b * HH + i) * LL + l];
        float ws = wsum[(b * HH + i) * CC + c];
        s_q[t] = w / fmaxf(ws, 1e-6f);
    }
    __syncthreads();
    int i = t >> 4, j = t & 15;
    float sdot = 0.f;
#pragma unroll
    for (int c = 0; c < CC; c++) sdot += s_q[i * 4 + c] * s_c[j * 4 + c];
    float mi_p = fminf(sdot, 1.f);
    float val = (i != j) ? logf(1.f - mi_p + 1e-6f) : 0.f;
    float tot = block_sum256(val, s_red);
    if (t == 0) atomicAdd(mi_out + b, -10.f * tot * (1.0f / ((float)LL * HH * HH)));
}

// ---------------- launcher ----------------
extern "C" void kernel_launch(void* const* d_in, const int* in_sizes, int n_in,
                              void* d_out, int out_size, void* d_ws, size_t ws_size,
                              hipStream_t stream) {
    (void)in_sizes; (void)n_in; (void)out_size; (void)ws_size;
    const float* query  = (const float*)d_in[0];
    const float* key    = (const float*)d_in[1];
    const float* value  = (const float*)d_in[2];
    const float* Wq     = (const float*)d_in[3];
    const float* bq     = (const float*)d_in[4];
    const float* Wk     = (const float*)d_in[5];
    const float* bk     = (const float*)d_in[6];
    const float* Wv     = (const float*)d_in[7];
    const float* bv     = (const float*)d_in[8];
    const float* Wo     = (const float*)d_in[9];
    const float* bo     = (const float*)d_in[10];
    const float* Wsem   = (const float*)d_in[11];
    const float* bsem   = (const float*)d_in[12];
    const float* Whead  = (const float*)d_in[13];
    const float* bhead  = (const float*)d_in[14];
    const float* tokmu  = (const float*)d_in[15];
    const float* toklv  = (const float*)d_in[16];
    const float* toklp  = (const float*)d_in[17];
    const float* headmu = (const float*)d_in[18];
    const float* headlv = (const float*)d_in[19];
    const float* headlp = (const float*)d_in[20];

    float* ws   = (float*)d_ws;
    const size_t NBLD = (size_t)BB * LL * DD;      // 4194304
    float* q    = ws;                               // fp32 q (cluster/alv need it)
    float* ctxf = ws + NBLD;
    float* alvq = ws + 2 * NBLD;
    float* alvh = alvq + (size_t)BB * HH * LL;
    float* cpq  = alvh + (size_t)BB * HH * LL;
    float* cph  = cpq + (size_t)BB * HH * LL * CC;
    float* lpdfh= cph + (size_t)BB * HH * LL * CC;
    float* pdfb = lpdfh + (size_t)BB * HH * LL * CC;
    float* wsumb= pdfb + (size_t)BB * HH * LL;
    unsigned int* maxenc = (unsigned int*)(wsumb + (size_t)BB * HH * CC);
    float* attn_h = (float*)(maxenc + 4);           // 67 MB region: per-head attn planes

    // bf16 scratch (ushort)
    unsigned short* us = (unsigned short*)(attn_h + (size_t)BB * 8 * LL * LL);
    const size_t WSZ = (size_t)DD * DD;            // 1048576
    unsigned short* qoh = us;                      // [qoh,qol,koh,kol,voh,vol] consecutive
    unsigned short* qol = qoh + NBLD;
    unsigned short* koh = qol + NBLD;
    unsigned short* kol = koh + NBLD;
    unsigned short* voh = kol + NBLD;
    unsigned short* vol = voh + NBLD;
    unsigned short* vth = vol + NBLD;              // Vt[d][l] per (b,h)
    unsigned short* vtl = vth + NBLD;
    unsigned short* wqh = vtl + NBLD;              // [Wq_h,Wq_l,Wk_h,Wk_l,Wv_h,Wv_l,Wo_h,Wo_l]
    unsigned short* woh = wqh + 6 * WSZ;
    unsigned short* wol = woh + WSZ;
    unsigned short* cxh = wol + WSZ;               // ctx hi/lo (attn3 epilogue -> Wo GEMM)
    unsigned short* cxl = cxh + NBLD;

    float* out      = (float*)d_out;
    float* attn_out = out + NBLD;
    float* kl_out   = attn_out + (size_t)BB * LL * LL;
    float* div_out  = kl_out + BB;
    float* mi_out   = div_out + BB;

    hipMemsetAsync(kl_out, 0, 3 * BB * sizeof(float), stream);
    hipMemsetAsync(maxenc, 0, sizeof(unsigned int), stream);

    // all 4 weight transposes in one launch (1024 blocks)
    wconv4<<<dim3(16, 16, 4), 256, 0, stream>>>(Wq, Wk, Wv, Wo, wqh);

    // batched q/k/v GEMM reading raw fp32 inputs (in-register hi/lo split, dist-1 prefetch)
    mfma_gemm_qkv<<<dim3(768), 256, 0, stream>>>(
        query, key, value, wqh, bq, bk, bv, q, qoh);

    // V transpose hi+lo in one launch (1024 blocks)
    vt_prep2<<<dim3(2 * LL / 128, HH, BB), 256, 0, stream>>>(voh, vol, vth, vtl);

    alv_gemm<<<BB * LL / 16, 256, 0, stream>>>(q, Wsem, bsem, alvq);
    cluster_kernel<<<BB * HH * 2, 256, 0, stream>>>(q, alvq, tokmu, toklv, toklp,
                                                    cpq, nullptr, nullptr, kl_out, 0);
    pairstats_kernel<<<BB * HH * 8, 256, 0, stream>>>(cpq, div_out, nullptr, 0);

    // attention: 8 heads per pass; epilogue emits ctx fp32 + hi/lo bf16
    for (int h0 = 0; h0 < HH; h0 += 8) {
        attn3_kernel<<<dim3(2048), 256, 0, stream>>>(
            qoh, qol, koh, kol, vth, vtl, cpq, ctxf, cxh, cxl, attn_h, h0);
        attn_reduce<<<BB * LL * LL / 4 / 256, 256, 0, stream>>>(
            attn_h, attn_out, h0 > 0 ? 1 : 0);
    }

    alv_gemm<<<BB * LL / 16, 256, 0, stream>>>(ctxf, Whead, bhead, alvh);
    cluster_kernel<<<BB * HH * 2, 256, 0, stream>>>(ctxf, alvh, headmu, headlv, headlp,
                                                    cph, lpdfh, maxenc, kl_out, 1);
    pairstats_kernel<<<BB * HH * 8, 256, 0, stream>>>(cph, div_out, mi_out, 1);
    wsum_kernel<<<BB * HH, 256, 0, stream>>>(lpdfh, cph, maxenc, pdfb, wsumb);
    mi_kernel<<<BB * LL, 256, 0, stream>>>(cph, pdfb, wsumb, mi_out);
    mfma_gemm_bias<<<dim3(256), 256, 0, stream>>>(
        cxh, cxl, woh, wol, bo, out);
}